// Round 4
// baseline (477.552 us; speedup 1.0000x reference)
//
#include <hip/hip_runtime.h>
#include <hip/hip_cooperative_groups.h>

namespace cg = cooperative_groups;

// Problem constants
#define BB 8
#define HWSZ 65536             // 256*256
#define PLANE (3 * HWSZ)       // one batch's [3,H,W]
#define OUTSTRIDE (BB * PLANE) // one full output tensor [8,3,256,256]

// ---------------------------------------------------------------------------
// Single cooperative kernel: 4 tiny GEMM stages + render, grid.sync() between.
// Grid 512 x 256. LDS aliased across stages (max 6656 floats = 26 KB).
__global__ __launch_bounds__(256, 2) void k_fused(
    const float* __restrict__ f, const float* __restrict__ bf,
    const float* __restrict__ pw1, const float* __restrict__ pb1,
    const float* __restrict__ pw2, const float* __restrict__ pb2,
    const float* __restrict__ fw1, const float* __restrict__ fb1,
    const float* __restrict__ fw2, const float* __restrict__ fb2,
    const float* __restrict__ x, float* __restrict__ out,
    float* __restrict__ ws) {
  cg::grid_group grid = cg::this_grid();
  __shared__ float smem[6656];

  float* h     = ws;          // [4,8,192]
  float* outs  = ws + 6144;   // [4,8,192]
  float* hc    = ws + 12288;  // [8,192]
  float* param = ws + 13824;  // [8,192]

  int t = threadIdx.x;
  int blk = blockIdx.x;

  // ---- Stage 1: h[k,b,:] = relu(feat @ W1[k] + b1[k]) -- blocks 0..47 ----
  if (blk < 48) {
    int k = blk / 12, ot = blk - k * 12, ob = ot * 16;
    int o = t & 15, s = t >> 4;
    float* sf  = smem;          // 8*512 = 4096
    float* red = smem + 4096;   // 16*128 = 2048
    const float* feat = (k & 1) ? bf : f;
    for (int idx = t; idx < 4096; idx += 256) sf[idx] = feat[idx];
    const float* w = pw1 + (size_t)k * (512 * 192) + ob + o;
    float wr[32];
#pragma unroll
    for (int j = 0; j < 32; ++j) wr[j] = w[(size_t)(s + 16 * j) * 192];
    __syncthreads();
    float acc[8];
#pragma unroll
    for (int b = 0; b < 8; ++b) {
      float a = 0.f;
      const float* sfb = sf + b * 512 + s;
#pragma unroll
      for (int j = 0; j < 32; ++j) a = fmaf(wr[j], sfb[16 * j], a);
      acc[b] = a;
    }
#pragma unroll
    for (int b = 0; b < 8; ++b) red[s * 128 + b * 16 + o] = acc[b];
    __syncthreads();
    if (t < 128) {
      float a = 0.f;
#pragma unroll
      for (int s2 = 0; s2 < 16; ++s2) a += red[s2 * 128 + t];
      int b = t >> 4, oo = t & 15;
      a += pb1[k * 192 + ob + oo];
      h[(k * 8 + b) * 192 + ob + oo] = fmaxf(a, 0.f);
    }
  }
  __threadfence();
  grid.sync();

  // ---- Stage 2: outs[k,b,:] = h @ W2[k] + b2[k] -- blocks 0..47 ----
  if (blk < 48) {
    int k = blk / 12, ot = blk - k * 12, ob = ot * 16;
    int o = t & 15, s = t >> 4;
    float* sh  = smem;          // 8*192 = 1536
    float* red = smem + 2048;   // 16*128 = 2048
    for (int idx = t; idx < 1536; idx += 256) sh[idx] = h[k * 1536 + idx];
    const float* w = pw2 + (size_t)k * (192 * 192) + ob + o;
    float wr[12];
#pragma unroll
    for (int j = 0; j < 12; ++j) wr[j] = w[(size_t)(s + 16 * j) * 192];
    __syncthreads();
    float acc[8];
#pragma unroll
    for (int b = 0; b < 8; ++b) {
      float a = 0.f;
      const float* shb = sh + b * 192 + s;
#pragma unroll
      for (int j = 0; j < 12; ++j) a = fmaf(wr[j], shb[16 * j], a);
      acc[b] = a;
    }
#pragma unroll
    for (int b = 0; b < 8; ++b) red[s * 128 + b * 16 + o] = acc[b];
    __syncthreads();
    if (t < 128) {
      float a = 0.f;
#pragma unroll
      for (int s2 = 0; s2 < 16; ++s2) a += red[s2 * 128 + t];
      int b = t >> 4, oo = t & 15;
      outs[(k * 8 + b) * 192 + ob + oo] = a + pb2[k * 192 + ob + oo];
    }
  }
  __threadfence();
  grid.sync();

  // ---- Stage 3: hc = relu(cat @ fW1 + fb1), cat = [o0,o1,o2+o3] -- blocks 0..23 ----
  if (blk < 24) {
    int ob = blk * 8;
    int o = t & 7, s = t >> 3;
    float* sc  = smem;          // 8*576 = 4608
    float* red = smem + 4608;   // 32*64 = 2048
    for (int idx = t; idx < 4608; idx += 256) {
      int b = idx / 576, i = idx - b * 576;
      float v;
      if (i < 192)      v = outs[(0 * 8 + b) * 192 + i];
      else if (i < 384) v = outs[(1 * 8 + b) * 192 + (i - 192)];
      else              v = outs[(2 * 8 + b) * 192 + (i - 384)] +
                            outs[(3 * 8 + b) * 192 + (i - 384)];
      sc[idx] = v;
    }
    const float* w = fw1 + ob + o;
    float wr[18];
#pragma unroll
    for (int j = 0; j < 18; ++j) wr[j] = w[(size_t)(s + 32 * j) * 192];
    __syncthreads();
    float acc[8];
#pragma unroll
    for (int b = 0; b < 8; ++b) {
      float a = 0.f;
      const float* scb = sc + b * 576 + s;
#pragma unroll
      for (int j = 0; j < 18; ++j) a = fmaf(wr[j], scb[32 * j], a);
      acc[b] = a;
    }
#pragma unroll
    for (int b = 0; b < 8; ++b) red[s * 64 + b * 8 + o] = acc[b];
    __syncthreads();
    if (t < 64) {
      float a = 0.f;
#pragma unroll
      for (int s2 = 0; s2 < 32; ++s2) a += red[s2 * 64 + t];
      int b = t >> 3, oo = t & 7;
      a += fb1[ob + oo];
      hc[b * 192 + ob + oo] = fmaxf(a, 0.f);
    }
  }
  __threadfence();
  grid.sync();

  // ---- Stage 4: param = hc @ fW2 + fb2 -- blocks 0..23 ----
  if (blk < 24) {
    int ob = blk * 8;
    int o = t & 7, s = t >> 3;
    float* sh  = smem;          // 1536
    float* red = smem + 2048;   // 2048
    for (int idx = t; idx < 1536; idx += 256) sh[idx] = hc[idx];
    const float* w = fw2 + ob + o;
    float wr[6];
#pragma unroll
    for (int j = 0; j < 6; ++j) wr[j] = w[(size_t)(s + 32 * j) * 192];
    __syncthreads();
    float acc[8];
#pragma unroll
    for (int b = 0; b < 8; ++b) {
      float a = 0.f;
      const float* shb = sh + b * 192 + s;
#pragma unroll
      for (int j = 0; j < 6; ++j) a = fmaf(wr[j], shb[32 * j], a);
      acc[b] = a;
    }
#pragma unroll
    for (int b = 0; b < 8; ++b) red[s * 64 + b * 8 + o] = acc[b];
    __syncthreads();
    if (t < 64) {
      float a = 0.f;
#pragma unroll
      for (int s2 = 0; s2 < 32; ++s2) a += red[s2 * 64 + t];
      int b = t >> 3, oo = t & 7;
      param[b * 192 + ob + oo] = a + fb2[ob + oo];
    }
  }
  __threadfence();
  grid.sync();

  // ---- Stage 5: render -- all 512 blocks (b = blk>>6, chunk = blk&63) ----
  {
    int b = blk >> 6, chunk = blk & 63;
    float* sp    = smem;         // [9][64] = 576
    float* sS    = smem + 576;   // [9][65] = 585
    float* snorm = smem + 1161;  // 9

    for (int idx = t; idx < 576; idx += 256) {
      int cur = idx >> 6, i = idx & 63;
      int oi = cur / 3, c = cur - oi * 3;
      sp[cur * 64 + i] = (oi == 0) ? param[b * 192 + c * 64 + i]
                                   : outs[((oi - 1) * 8 + b) * 192 + c * 64 + i];
    }
    __syncthreads();
    if (t < 9) {
      float s = 0.f;
      sS[t * 65 + 0] = 0.f;
      for (int i = 0; i < 64; ++i) { s += sp[t * 64 + i]; sS[t * 65 + i + 1] = s; }
      snorm[t] = 64.f / (s + 1e-30f);
    }
    __syncthreads();

    auto ev = [&](int cur, float v) -> float {
      int k = (int)(v * 64.f);
      k = k < 0 ? 0 : (k > 63 ? 63 : k);
      float tt = v - (float)k * 0.015625f;
      return fmaf(sS[cur * 65 + k], 0.015625f, tt * sp[cur * 64 + k]) * snorm[cur];
    };
    auto ev4 = [&](int cur, float4 v) -> float4 {
      float4 r;
      r.x = ev(cur, v.x); r.y = ev(cur, v.y);
      r.z = ev(cur, v.z); r.w = ev(cur, v.w);
      return r;
    };

    int s4 = chunk * 256 + t;
    const float* xb = x + (size_t)b * PLANE;
    float4 vr = ((const float4*)(xb))[s4];
    float4 vg = ((const float4*)(xb + HWSZ))[s4];
    float4 vb = ((const float4*)(xb + 2 * HWSZ))[s4];

    float4 gr;
    gr.x = fmaf(0.299f, vr.x, fmaf(0.587f, vg.x, 0.114f * vb.x));
    gr.y = fmaf(0.299f, vr.y, fmaf(0.587f, vg.y, 0.114f * vb.y));
    gr.z = fmaf(0.299f, vr.z, fmaf(0.587f, vg.z, 0.114f * vb.z));
    gr.w = fmaf(0.299f, vr.w, fmaf(0.587f, vg.w, 0.114f * vb.w));

    float* o0 = out + (size_t)b * PLANE;
    float* o1 = out + OUTSTRIDE + (size_t)b * PLANE;
    float* o2 = out + 2 * OUTSTRIDE + (size_t)b * PLANE;

    ((float4*)(o0))[s4]            = ev4(0, vr);
    ((float4*)(o0 + HWSZ))[s4]     = ev4(1, vg);
    ((float4*)(o0 + 2 * HWSZ))[s4] = ev4(2, vb);
    ((float4*)(o1))[s4]            = ev4(3, gr);
    ((float4*)(o1 + HWSZ))[s4]     = ev4(4, gr);
    ((float4*)(o1 + 2 * HWSZ))[s4] = ev4(5, gr);
    ((float4*)(o2))[s4]            = ev4(6, gr);
    ((float4*)(o2 + HWSZ))[s4]     = ev4(7, gr);
    ((float4*)(o2 + 2 * HWSZ))[s4] = ev4(8, gr);
  }
}

// ---------------------------------------------------------------------------
extern "C" void kernel_launch(void* const* d_in, const int* in_sizes, int n_in,
                              void* d_out, int out_size, void* d_ws, size_t ws_size,
                              hipStream_t stream) {
  const float* x   = (const float*)d_in[0];
  const float* f   = (const float*)d_in[1];
  const float* bf  = (const float*)d_in[2];
  const float* pw1 = (const float*)d_in[3];
  const float* pb1 = (const float*)d_in[4];
  const float* pw2 = (const float*)d_in[5];
  const float* pb2 = (const float*)d_in[6];
  const float* fw1 = (const float*)d_in[7];
  const float* fb1 = (const float*)d_in[8];
  const float* fw2 = (const float*)d_in[9];
  const float* fb2 = (const float*)d_in[10];
  float* out = (float*)d_out;
  float* ws  = (float*)d_ws;

  void* args[] = {
      (void*)&f,   (void*)&bf,  (void*)&pw1, (void*)&pb1, (void*)&pw2,
      (void*)&pb2, (void*)&fw1, (void*)&fb1, (void*)&fw2, (void*)&fb2,
      (void*)&x,   (void*)&out, (void*)&ws};
  hipLaunchCooperativeKernel((void*)k_fused, dim3(512), dim3(256), args, 0,
                             stream);
}

// Round 5
// 116.120 us; speedup vs baseline: 4.1126x; 4.1126x over previous
//
#include <hip/hip_runtime.h>

// Problem constants
#define HWSZ 65536             // 256*256
#define PLANE (3 * HWSZ)       // one batch's [3,H,W]
#define OUTSTRIDE (8 * PLANE)  // one full output tensor [8,3,256,256]
#define GBAR_MAGIC 0x1357A5A5

// Monotone-counter global barrier for a 48-block grid (all trivially
// co-resident on 256 CUs). cnt/flag live in d_ws (0xAA-poisoned each call);
// block 0 re-inits them every launch, others gate on the magic flag before
// their first arrival.
__device__ __forceinline__ void gbar(int* cnt, int* flag, int target, bool first) {
  __syncthreads();  // drains vmcnt -> this block's stores are at least in L2
  if (threadIdx.x == 0) {
    if (first) {
      while (atomicAdd(flag, 0) != GBAR_MAGIC) __builtin_amdgcn_s_sleep(2);
    }
    __threadfence();          // release: write back L2 (device scope)
    atomicAdd(cnt, 1);
    while (atomicAdd(cnt, 0) < target) __builtin_amdgcn_s_sleep(2);
    __threadfence();          // acquire: invalidate stale lines
  }
  __syncthreads();
}

// ---------------------------------------------------------------------------
// One kernel, 48 blocks x 256: proj L1 | bar | proj L2 | bar | fcat L1 | bar |
// fcat L2. Stage bodies identical to the verified round-3 kernels.
__global__ __launch_bounds__(256) void k_mlp(
    const float* __restrict__ f, const float* __restrict__ bf,
    const float* __restrict__ pw1, const float* __restrict__ pb1,
    const float* __restrict__ pw2, const float* __restrict__ pb2,
    const float* __restrict__ fw1, const float* __restrict__ fb1,
    const float* __restrict__ fw2, const float* __restrict__ fb2,
    float* __restrict__ ws) {
  __shared__ float smem[6656];
  int t = threadIdx.x, blk = blockIdx.x;

  float* h     = ws;          // [4,8,192]
  float* outs  = ws + 6144;   // [4,8,192]
  float* hc    = ws + 12288;  // [8,192]
  float* param = ws + 13824;  // [8,192]
  int* cnt  = (int*)(ws + 16384);
  int* flag = (int*)(ws + 16384) + 32;

  if (blk == 0 && t == 0) {
    atomicExch(cnt, 0);
    __threadfence();
    atomicExch(flag, GBAR_MAGIC);
  }

  // ---- Stage 1: h[k,b,:] = relu(feat @ W1[k] + b1[k]) ----
  {
    int k = blk / 12, ot = blk - k * 12, ob = ot * 16;
    int o = t & 15, s = t >> 4;
    float* sf  = smem;         // 4096
    float* red = smem + 4096;  // 2048
    const float* feat = (k & 1) ? bf : f;
    for (int idx = t; idx < 4096; idx += 256) sf[idx] = feat[idx];
    const float* w = pw1 + (size_t)k * (512 * 192) + ob + o;
    float wr[32];
#pragma unroll
    for (int j = 0; j < 32; ++j) wr[j] = w[(size_t)(s + 16 * j) * 192];
    __syncthreads();
    float acc[8];
#pragma unroll
    for (int b = 0; b < 8; ++b) {
      float a = 0.f;
      const float* sfb = sf + b * 512 + s;
#pragma unroll
      for (int j = 0; j < 32; ++j) a = fmaf(wr[j], sfb[16 * j], a);
      acc[b] = a;
    }
#pragma unroll
    for (int b = 0; b < 8; ++b) red[s * 128 + b * 16 + o] = acc[b];
    __syncthreads();
    if (t < 128) {
      float a = 0.f;
#pragma unroll
      for (int s2 = 0; s2 < 16; ++s2) a += red[s2 * 128 + t];
      int b = t >> 4, oo = t & 15;
      a += pb1[k * 192 + ob + oo];
      h[(k * 8 + b) * 192 + ob + oo] = fmaxf(a, 0.f);
    }
  }
  gbar(cnt, flag, 48, true);

  // ---- Stage 2: outs[k,b,:] = h @ W2[k] + b2[k] ----
  {
    int k = blk / 12, ot = blk - k * 12, ob = ot * 16;
    int o = t & 15, s = t >> 4;
    float* sh  = smem;         // 1536
    float* red = smem + 2048;  // 2048
    for (int idx = t; idx < 1536; idx += 256) sh[idx] = h[k * 1536 + idx];
    const float* w = pw2 + (size_t)k * (192 * 192) + ob + o;
    float wr[12];
#pragma unroll
    for (int j = 0; j < 12; ++j) wr[j] = w[(size_t)(s + 16 * j) * 192];
    __syncthreads();
    float acc[8];
#pragma unroll
    for (int b = 0; b < 8; ++b) {
      float a = 0.f;
      const float* shb = sh + b * 192 + s;
#pragma unroll
      for (int j = 0; j < 12; ++j) a = fmaf(wr[j], shb[16 * j], a);
      acc[b] = a;
    }
#pragma unroll
    for (int b = 0; b < 8; ++b) red[s * 128 + b * 16 + o] = acc[b];
    __syncthreads();
    if (t < 128) {
      float a = 0.f;
#pragma unroll
      for (int s2 = 0; s2 < 16; ++s2) a += red[s2 * 128 + t];
      int b = t >> 4, oo = t & 15;
      outs[(k * 8 + b) * 192 + ob + oo] = a + pb2[k * 192 + ob + oo];
    }
  }
  gbar(cnt, flag, 96, false);

  // ---- Stage 3: hc = relu(cat @ fW1 + fb1), blocks 0..23 ----
  if (blk < 24) {
    int ob = blk * 8;
    int o = t & 7, s = t >> 3;
    float* sc  = smem;         // 4608
    float* red = smem + 4608;  // 2048
    for (int idx = t; idx < 4608; idx += 256) {
      int b = idx / 576, i = idx - b * 576;
      float v;
      if (i < 192)      v = outs[(0 * 8 + b) * 192 + i];
      else if (i < 384) v = outs[(1 * 8 + b) * 192 + (i - 192)];
      else              v = outs[(2 * 8 + b) * 192 + (i - 384)] +
                            outs[(3 * 8 + b) * 192 + (i - 384)];
      sc[idx] = v;
    }
    const float* w = fw1 + ob + o;
    float wr[18];
#pragma unroll
    for (int j = 0; j < 18; ++j) wr[j] = w[(size_t)(s + 32 * j) * 192];
    __syncthreads();
    float acc[8];
#pragma unroll
    for (int b = 0; b < 8; ++b) {
      float a = 0.f;
      const float* scb = sc + b * 576 + s;
#pragma unroll
      for (int j = 0; j < 18; ++j) a = fmaf(wr[j], scb[32 * j], a);
      acc[b] = a;
    }
#pragma unroll
    for (int b = 0; b < 8; ++b) red[s * 64 + b * 8 + o] = acc[b];
    __syncthreads();
    if (t < 64) {
      float a = 0.f;
#pragma unroll
      for (int s2 = 0; s2 < 32; ++s2) a += red[s2 * 64 + t];
      int b = t >> 3, oo = t & 7;
      a += fb1[ob + oo];
      hc[b * 192 + ob + oo] = fmaxf(a, 0.f);
    }
  }
  gbar(cnt, flag, 144, false);

  // ---- Stage 4: param = hc @ fW2 + fb2, blocks 0..23 ----
  if (blk < 24) {
    int ob = blk * 8;
    int o = t & 7, s = t >> 3;
    float* sh  = smem;         // 1536
    float* red = smem + 2048;  // 2048
    for (int idx = t; idx < 1536; idx += 256) sh[idx] = hc[idx];
    const float* w = fw2 + ob + o;
    float wr[6];
#pragma unroll
    for (int j = 0; j < 6; ++j) wr[j] = w[(size_t)(s + 32 * j) * 192];
    __syncthreads();
    float acc[8];
#pragma unroll
    for (int b = 0; b < 8; ++b) {
      float a = 0.f;
      const float* shb = sh + b * 192 + s;
#pragma unroll
      for (int j = 0; j < 6; ++j) a = fmaf(wr[j], shb[32 * j], a);
      acc[b] = a;
    }
#pragma unroll
    for (int b = 0; b < 8; ++b) red[s * 64 + b * 8 + o] = acc[b];
    __syncthreads();
    if (t < 64) {
      float a = 0.f;
#pragma unroll
      for (int s2 = 0; s2 < 32; ++s2) a += red[s2 * 64 + t];
      int b = t >> 3, oo = t & 7;
      param[b * 192 + ob + oo] = a + fb2[ob + oo];
    }
  }
  // kernel end is the sync point for the render node
}

// ---------------------------------------------------------------------------
// Render: per curve, fused LUT entry e[k] = {S_k*norm/64, p_k*norm} so each
// eval is one ds_read_b64 gather + one FMA: out = fmaf(v - k/64, e.y, e.x).
__global__ __launch_bounds__(256) void k_render(
    const float* __restrict__ x, const float* __restrict__ ws,
    float* __restrict__ out) {
  int b = blockIdx.y, t = threadIdx.x;
  const float* outs  = ws + 6144;
  const float* param = ws + 13824;
  __shared__ float sp[576];
  __shared__ float2 tab[576];

  for (int idx = t; idx < 576; idx += 256) {
    int cur = idx >> 6, i = idx & 63;
    int oi = cur / 3, c = cur - oi * 3;
    sp[cur * 64 + i] = (oi == 0) ? param[b * 192 + c * 64 + i]
                                 : outs[((oi - 1) * 8 + b) * 192 + c * 64 + i];
  }
  __syncthreads();
  if (t < 9) {
    float sum = 0.f;
    for (int i = 0; i < 64; ++i) sum += sp[t * 64 + i];
    float norm = 64.f / (sum + 1e-30f);
    float run = 0.f;
    for (int i = 0; i < 64; ++i) {
      float p = sp[t * 64 + i];
      tab[t * 64 + i] = make_float2(run * 0.015625f * norm, p * norm);
      run += p;
    }
  }
  __syncthreads();

  auto ev = [&](int cur, float v) -> float {
    int k = (int)(v * 64.f);
    k = k < 0 ? 0 : (k > 63 ? 63 : k);
    float2 e = tab[cur * 64 + k];
    float tt = v - (float)k * 0.015625f;
    return fmaf(tt, e.y, e.x);
  };
  auto ev4 = [&](int cur, float4 v) -> float4 {
    float4 r;
    r.x = ev(cur, v.x); r.y = ev(cur, v.y);
    r.z = ev(cur, v.z); r.w = ev(cur, v.w);
    return r;
  };

  int s4 = blockIdx.x * 256 + t;
  const float* xb = x + (size_t)b * PLANE;
  float4 vr = ((const float4*)(xb))[s4];
  float4 vg = ((const float4*)(xb + HWSZ))[s4];
  float4 vb = ((const float4*)(xb + 2 * HWSZ))[s4];

  float4 gr;
  gr.x = fmaf(0.299f, vr.x, fmaf(0.587f, vg.x, 0.114f * vb.x));
  gr.y = fmaf(0.299f, vr.y, fmaf(0.587f, vg.y, 0.114f * vb.y));
  gr.z = fmaf(0.299f, vr.z, fmaf(0.587f, vg.z, 0.114f * vb.z));
  gr.w = fmaf(0.299f, vr.w, fmaf(0.587f, vg.w, 0.114f * vb.w));

  float* o0 = out + (size_t)b * PLANE;
  float* o1 = out + OUTSTRIDE + (size_t)b * PLANE;
  float* o2 = out + 2 * OUTSTRIDE + (size_t)b * PLANE;

  ((float4*)(o0))[s4]            = ev4(0, vr);
  ((float4*)(o0 + HWSZ))[s4]     = ev4(1, vg);
  ((float4*)(o0 + 2 * HWSZ))[s4] = ev4(2, vb);
  ((float4*)(o1))[s4]            = ev4(3, gr);
  ((float4*)(o1 + HWSZ))[s4]     = ev4(4, gr);
  ((float4*)(o1 + 2 * HWSZ))[s4] = ev4(5, gr);
  ((float4*)(o2))[s4]            = ev4(6, gr);
  ((float4*)(o2 + HWSZ))[s4]     = ev4(7, gr);
  ((float4*)(o2 + 2 * HWSZ))[s4] = ev4(8, gr);
}

// ---------------------------------------------------------------------------
extern "C" void kernel_launch(void* const* d_in, const int* in_sizes, int n_in,
                              void* d_out, int out_size, void* d_ws, size_t ws_size,
                              hipStream_t stream) {
  const float* x   = (const float*)d_in[0];
  const float* f   = (const float*)d_in[1];
  const float* bf  = (const float*)d_in[2];
  const float* pw1 = (const float*)d_in[3];
  const float* pb1 = (const float*)d_in[4];
  const float* pw2 = (const float*)d_in[5];
  const float* pb2 = (const float*)d_in[6];
  const float* fw1 = (const float*)d_in[7];
  const float* fb1 = (const float*)d_in[8];
  const float* fw2 = (const float*)d_in[9];
  const float* fb2 = (const float*)d_in[10];
  float* out = (float*)d_out;
  float* ws  = (float*)d_ws;

  k_mlp<<<48, 256, 0, stream>>>(f, bf, pw1, pb1, pw2, pb2, fw1, fb1, fw2, fb2,
                                ws);
  dim3 grid(64, 8);
  k_render<<<grid, 256, 0, stream>>>(x, ws, out);
}

// Round 6
// 105.106 us; speedup vs baseline: 4.5435x; 1.1048x over previous
//
#include <hip/hip_runtime.h>

// Problem constants
#define HWSZ 65536             // 256*256
#define PLANE (3 * HWSZ)       // one batch's [3,H,W]
#define OUTSTRIDE (8 * PLANE)  // one full output tensor [8,3,256,256]

// ---------------------------------------------------------------------------
// Fused projection: one block per (k,b). Block 192 = (s = 4 K-splits) x
// (q = 48 output-quads). Weights streamed as contiguous float4 rows in
// explicit 16-deep batches so ~16 loads stay in flight per thread.
__global__ __launch_bounds__(192) void k_proj(
    const float* __restrict__ f, const float* __restrict__ bf,
    const float* __restrict__ pw1, const float* __restrict__ pb1,
    const float* __restrict__ pw2, const float* __restrict__ pb2,
    float* __restrict__ outs) {
  int k = blockIdx.x >> 3, b = blockIdx.x & 7;
  int t = threadIdx.x, q = t % 48, s = t / 48;  // s in 0..3
  __shared__ float sf[512];
  __shared__ float4 red4[4 * 48];  // float view: red[s*192 + o]
  __shared__ float sh[192];

  const float* feat = ((k & 1) ? bf : f) + b * 512;
  for (int i = t; i < 512; i += 192) sf[i] = feat[i];
  __syncthreads();

  // stage 1: 512 -> 192 (this thread: outputs 4q..4q+4, K slice s*128..+128)
  {
    const float4* w = (const float4*)(pw1 + (size_t)k * (512 * 192));
    float4 acc = {0.f, 0.f, 0.f, 0.f};
    int i0 = s * 128;
    for (int r = 0; r < 8; ++r) {
      float4 wv[16];
#pragma unroll
      for (int j = 0; j < 16; ++j)
        wv[j] = w[(size_t)(i0 + r * 16 + j) * 48 + q];
#pragma unroll
      for (int j = 0; j < 16; ++j) {
        float v = sf[i0 + r * 16 + j];
        acc.x = fmaf(v, wv[j].x, acc.x); acc.y = fmaf(v, wv[j].y, acc.y);
        acc.z = fmaf(v, wv[j].z, acc.z); acc.w = fmaf(v, wv[j].w, acc.w);
      }
    }
    red4[s * 48 + q] = acc;
  }
  __syncthreads();
  {
    const float* red = (const float*)red4;
    float a = red[t] + red[192 + t] + red[384 + t] + red[576 + t] +
              pb1[k * 192 + t];
    sh[t] = fmaxf(a, 0.f);
  }
  __syncthreads();

  // stage 2: 192 -> 192 (K slice s*48..+48)
  {
    const float4* w = (const float4*)(pw2 + (size_t)k * (192 * 192));
    float4 acc = {0.f, 0.f, 0.f, 0.f};
    int i0 = s * 48;
    for (int r = 0; r < 3; ++r) {
      float4 wv[16];
#pragma unroll
      for (int j = 0; j < 16; ++j)
        wv[j] = w[(size_t)(i0 + r * 16 + j) * 48 + q];
#pragma unroll
      for (int j = 0; j < 16; ++j) {
        float v = sh[i0 + r * 16 + j];
        acc.x = fmaf(v, wv[j].x, acc.x); acc.y = fmaf(v, wv[j].y, acc.y);
        acc.z = fmaf(v, wv[j].z, acc.z); acc.w = fmaf(v, wv[j].w, acc.w);
      }
    }
    red4[s * 48 + q] = acc;
  }
  __syncthreads();
  {
    const float* red = (const float*)red4;
    outs[(k * 8 + b) * 192 + t] = red[t] + red[192 + t] + red[384 + t] +
                                  red[576 + t] + pb2[k * 192 + t];
  }
}

// ---------------------------------------------------------------------------
// Fused final MLP: one block per b. cat = [outs0, outs1, outs2+outs3] (576).
__global__ __launch_bounds__(192) void k_fcat(
    const float* __restrict__ outs, const float* __restrict__ fw1,
    const float* __restrict__ fb1, const float* __restrict__ fw2,
    const float* __restrict__ fb2, float* __restrict__ param) {
  int b = blockIdx.x;
  int t = threadIdx.x, q = t % 48, s = t / 48;
  __shared__ float sc[576];
  __shared__ float4 red4[4 * 48];
  __shared__ float sh[192];

  for (int idx = t; idx < 576; idx += 192) {
    float v;
    if (idx < 192)      v = outs[(0 * 8 + b) * 192 + idx];
    else if (idx < 384) v = outs[(1 * 8 + b) * 192 + (idx - 192)];
    else                v = outs[(2 * 8 + b) * 192 + (idx - 384)] +
                            outs[(3 * 8 + b) * 192 + (idx - 384)];
    sc[idx] = v;
  }
  __syncthreads();

  // stage 1: 576 -> 192 (K slice s*144..+144, 9 rounds of 16)
  {
    const float4* w = (const float4*)fw1;
    float4 acc = {0.f, 0.f, 0.f, 0.f};
    int i0 = s * 144;
    for (int r = 0; r < 9; ++r) {
      float4 wv[16];
#pragma unroll
      for (int j = 0; j < 16; ++j)
        wv[j] = w[(size_t)(i0 + r * 16 + j) * 48 + q];
#pragma unroll
      for (int j = 0; j < 16; ++j) {
        float v = sc[i0 + r * 16 + j];
        acc.x = fmaf(v, wv[j].x, acc.x); acc.y = fmaf(v, wv[j].y, acc.y);
        acc.z = fmaf(v, wv[j].z, acc.z); acc.w = fmaf(v, wv[j].w, acc.w);
      }
    }
    red4[s * 48 + q] = acc;
  }
  __syncthreads();
  {
    const float* red = (const float*)red4;
    float a = red[t] + red[192 + t] + red[384 + t] + red[576 + t] + fb1[t];
    sh[t] = fmaxf(a, 0.f);
  }
  __syncthreads();

  // stage 2: 192 -> 192
  {
    const float4* w = (const float4*)fw2;
    float4 acc = {0.f, 0.f, 0.f, 0.f};
    int i0 = s * 48;
    for (int r = 0; r < 3; ++r) {
      float4 wv[16];
#pragma unroll
      for (int j = 0; j < 16; ++j)
        wv[j] = w[(size_t)(i0 + r * 16 + j) * 48 + q];
#pragma unroll
      for (int j = 0; j < 16; ++j) {
        float v = sh[i0 + r * 16 + j];
        acc.x = fmaf(v, wv[j].x, acc.x); acc.y = fmaf(v, wv[j].y, acc.y);
        acc.z = fmaf(v, wv[j].z, acc.z); acc.w = fmaf(v, wv[j].w, acc.w);
      }
    }
    red4[s * 48 + q] = acc;
  }
  __syncthreads();
  {
    const float* red = (const float*)red4;
    param[b * 192 + t] = red[t] + red[192 + t] + red[384 + t] + red[576 + t] +
                         fb2[t];
  }
}

// ---------------------------------------------------------------------------
// Render. LUT entry e[k] = {S_k*norm/64, p_k*norm}; eval = one b64 LDS gather
// + one FMA. LUT built with a per-wave prefix scan (width-64 shfl_up).
__global__ __launch_bounds__(256) void k_render(
    const float* __restrict__ x, const float* __restrict__ ws,
    float* __restrict__ out) {
  int b = blockIdx.y, t = threadIdx.x;
  int wave = t >> 6, lane = t & 63;
  const float* outs  = ws;
  const float* param = ws + 6144;
  __shared__ float2 tab[576];

  for (int cur = wave; cur < 9; cur += 4) {
    int oi = cur / 3, c = cur - oi * 3;
    const float* src = (oi == 0) ? param + b * 192 + c * 64
                                 : outs + ((oi - 1) * 8 + b) * 192 + c * 64;
    float p = src[lane];
    float v = p;  // inclusive scan
#pragma unroll
    for (int d = 1; d < 64; d <<= 1) {
      float n = __shfl_up(v, d, 64);
      if (lane >= d) v += n;
    }
    float total = __shfl(v, 63, 64);
    float norm = 64.f / (total + 1e-30f);
    float ex = v - p;  // exclusive prefix S_k
    tab[cur * 64 + lane] = make_float2(ex * 0.015625f * norm, p * norm);
  }
  __syncthreads();

  auto ev = [&](int cur, float v) -> float {
    int k = (int)(v * 64.f);
    k = k < 0 ? 0 : (k > 63 ? 63 : k);
    float2 e = tab[cur * 64 + k];
    float tt = v - (float)k * 0.015625f;
    return fmaf(tt, e.y, e.x);
  };
  auto ev4 = [&](int cur, float4 v) -> float4 {
    float4 r;
    r.x = ev(cur, v.x); r.y = ev(cur, v.y);
    r.z = ev(cur, v.z); r.w = ev(cur, v.w);
    return r;
  };

  int s4 = blockIdx.x * 256 + t;
  const float* xb = x + (size_t)b * PLANE;
  float4 vr = ((const float4*)(xb))[s4];
  float4 vg = ((const float4*)(xb + HWSZ))[s4];
  float4 vb = ((const float4*)(xb + 2 * HWSZ))[s4];

  float4 gr;
  gr.x = fmaf(0.299f, vr.x, fmaf(0.587f, vg.x, 0.114f * vb.x));
  gr.y = fmaf(0.299f, vr.y, fmaf(0.587f, vg.y, 0.114f * vb.y));
  gr.z = fmaf(0.299f, vr.z, fmaf(0.587f, vg.z, 0.114f * vb.z));
  gr.w = fmaf(0.299f, vr.w, fmaf(0.587f, vg.w, 0.114f * vb.w));

  float* o0 = out + (size_t)b * PLANE;
  float* o1 = out + OUTSTRIDE + (size_t)b * PLANE;
  float* o2 = out + 2 * OUTSTRIDE + (size_t)b * PLANE;

  ((float4*)(o0))[s4]            = ev4(0, vr);
  ((float4*)(o0 + HWSZ))[s4]     = ev4(1, vg);
  ((float4*)(o0 + 2 * HWSZ))[s4] = ev4(2, vb);
  ((float4*)(o1))[s4]            = ev4(3, gr);
  ((float4*)(o1 + HWSZ))[s4]     = ev4(4, gr);
  ((float4*)(o1 + 2 * HWSZ))[s4] = ev4(5, gr);
  ((float4*)(o2))[s4]            = ev4(6, gr);
  ((float4*)(o2 + HWSZ))[s4]     = ev4(7, gr);
  ((float4*)(o2 + 2 * HWSZ))[s4] = ev4(8, gr);
}

// ---------------------------------------------------------------------------
extern "C" void kernel_launch(void* const* d_in, const int* in_sizes, int n_in,
                              void* d_out, int out_size, void* d_ws, size_t ws_size,
                              hipStream_t stream) {
  const float* x   = (const float*)d_in[0];
  const float* f   = (const float*)d_in[1];
  const float* bf  = (const float*)d_in[2];
  const float* pw1 = (const float*)d_in[3];
  const float* pb1 = (const float*)d_in[4];
  const float* pw2 = (const float*)d_in[5];
  const float* pb2 = (const float*)d_in[6];
  const float* fw1 = (const float*)d_in[7];
  const float* fb1 = (const float*)d_in[8];
  const float* fw2 = (const float*)d_in[9];
  const float* fb2 = (const float*)d_in[10];
  float* out = (float*)d_out;
  float* ws  = (float*)d_ws;

  float* outs  = ws;         // [4,8,192] = 6144
  float* param = ws + 6144;  // [8,192]   = 1536

  k_proj<<<32, 192, 0, stream>>>(f, bf, pw1, pb1, pw2, pb2, outs);
  k_fcat<<<8, 192, 0, stream>>>(outs, fw1, fb1, fw2, fb2, param);
  dim3 grid(64, 8);
  k_render<<<grid, 256, 0, stream>>>(x, ws, out);
}

// Round 7
// 104.029 us; speedup vs baseline: 4.5906x; 1.0104x over previous
//
#include <hip/hip_runtime.h>

// Problem constants
#define HWSZ 65536             // 256*256
#define PLANE (3 * HWSZ)       // one batch's [3,H,W]
#define OUTSTRIDE (8 * PLANE)  // one full output tensor [8,3,256,256]

// ---------------------------------------------------------------------------
// Fused projection: one block per (k,b). Block 384 = (s = 8 K-splits) x
// (q = 48 output-quads). Weights streamed as contiguous float4 rows in
// 16-deep batches (~98 KB in flight per block -> ~2x round-6 stream rate).
__global__ __launch_bounds__(384) void k_proj(
    const float* __restrict__ f, const float* __restrict__ bf,
    const float* __restrict__ pw1, const float* __restrict__ pb1,
    const float* __restrict__ pw2, const float* __restrict__ pb2,
    float* __restrict__ outs) {
  int k = blockIdx.x >> 3, b = blockIdx.x & 7;
  int t = threadIdx.x, q = t % 48, s = t / 48;  // s in 0..7
  __shared__ float sf[512];
  __shared__ float red[8 * 192];
  __shared__ float sh[192];

  const float* feat = ((k & 1) ? bf : f) + b * 512;
  for (int i = t; i < 512; i += 384) sf[i] = feat[i];
  __syncthreads();

  // stage 1: 512 -> 192 (outputs 4q..4q+3, K slice s*64..+64)
  {
    const float4* w = (const float4*)(pw1 + (size_t)k * (512 * 192));
    float4 acc = {0.f, 0.f, 0.f, 0.f};
    int i0 = s * 64;
    for (int r = 0; r < 4; ++r) {
      float4 wv[16];
#pragma unroll
      for (int j = 0; j < 16; ++j)
        wv[j] = w[(size_t)(i0 + r * 16 + j) * 48 + q];
#pragma unroll
      for (int j = 0; j < 16; ++j) {
        float v = sf[i0 + r * 16 + j];
        acc.x = fmaf(v, wv[j].x, acc.x); acc.y = fmaf(v, wv[j].y, acc.y);
        acc.z = fmaf(v, wv[j].z, acc.z); acc.w = fmaf(v, wv[j].w, acc.w);
      }
    }
    ((float4*)(red + s * 192))[q] = acc;
  }
  __syncthreads();
  if (t < 192) {
    float a = pb1[k * 192 + t];
#pragma unroll
    for (int s2 = 0; s2 < 8; ++s2) a += red[s2 * 192 + t];
    sh[t] = fmaxf(a, 0.f);
  }
  __syncthreads();

  // stage 2: 192 -> 192 (K slice s*24..+24)
  {
    const float4* w = (const float4*)(pw2 + (size_t)k * (192 * 192));
    float4 acc = {0.f, 0.f, 0.f, 0.f};
    int i0 = s * 24;
    for (int r = 0; r < 2; ++r) {
      float4 wv[12];
#pragma unroll
      for (int j = 0; j < 12; ++j)
        wv[j] = w[(size_t)(i0 + r * 12 + j) * 48 + q];
#pragma unroll
      for (int j = 0; j < 12; ++j) {
        float v = sh[i0 + r * 12 + j];
        acc.x = fmaf(v, wv[j].x, acc.x); acc.y = fmaf(v, wv[j].y, acc.y);
        acc.z = fmaf(v, wv[j].z, acc.z); acc.w = fmaf(v, wv[j].w, acc.w);
      }
    }
    ((float4*)(red + s * 192))[q] = acc;
  }
  __syncthreads();
  if (t < 192) {
    float a = pb2[k * 192 + t];
#pragma unroll
    for (int s2 = 0; s2 < 8; ++s2) a += red[s2 * 192 + t];
    outs[(k * 8 + b) * 192 + t] = a;
  }
}

// ---------------------------------------------------------------------------
// Fused final MLP: one block per b, 384 threads = 8 K-splits x 48 quads.
// cat = [outs0, outs1, outs2+outs3] (576).
__global__ __launch_bounds__(384) void k_fcat(
    const float* __restrict__ outs, const float* __restrict__ fw1,
    const float* __restrict__ fb1, const float* __restrict__ fw2,
    const float* __restrict__ fb2, float* __restrict__ param) {
  int b = blockIdx.x;
  int t = threadIdx.x, q = t % 48, s = t / 48;
  __shared__ float sc[576];
  __shared__ float red[8 * 192];
  __shared__ float sh[192];

  for (int idx = t; idx < 576; idx += 384) {
    float v;
    if (idx < 192)      v = outs[(0 * 8 + b) * 192 + idx];
    else if (idx < 384) v = outs[(1 * 8 + b) * 192 + (idx - 192)];
    else                v = outs[(2 * 8 + b) * 192 + (idx - 384)] +
                            outs[(3 * 8 + b) * 192 + (idx - 384)];
    sc[idx] = v;
  }
  __syncthreads();

  // stage 1: 576 -> 192 (K slice s*72..+72, 4 rounds of 18)
  {
    const float4* w = (const float4*)fw1;
    float4 acc = {0.f, 0.f, 0.f, 0.f};
    int i0 = s * 72;
    for (int r = 0; r < 4; ++r) {
      float4 wv[18];
#pragma unroll
      for (int j = 0; j < 18; ++j)
        wv[j] = w[(size_t)(i0 + r * 18 + j) * 48 + q];
#pragma unroll
      for (int j = 0; j < 18; ++j) {
        float v = sc[i0 + r * 18 + j];
        acc.x = fmaf(v, wv[j].x, acc.x); acc.y = fmaf(v, wv[j].y, acc.y);
        acc.z = fmaf(v, wv[j].z, acc.z); acc.w = fmaf(v, wv[j].w, acc.w);
      }
    }
    ((float4*)(red + s * 192))[q] = acc;
  }
  __syncthreads();
  if (t < 192) {
    float a = fb1[t];
#pragma unroll
    for (int s2 = 0; s2 < 8; ++s2) a += red[s2 * 192 + t];
    sh[t] = fmaxf(a, 0.f);
  }
  __syncthreads();

  // stage 2: 192 -> 192 (K slice s*24..+24)
  {
    const float4* w = (const float4*)fw2;
    float4 acc = {0.f, 0.f, 0.f, 0.f};
    int i0 = s * 24;
    for (int r = 0; r < 2; ++r) {
      float4 wv[12];
#pragma unroll
      for (int j = 0; j < 12; ++j)
        wv[j] = w[(size_t)(i0 + r * 12 + j) * 48 + q];
#pragma unroll
      for (int j = 0; j < 12; ++j) {
        float v = sh[i0 + r * 12 + j];
        acc.x = fmaf(v, wv[j].x, acc.x); acc.y = fmaf(v, wv[j].y, acc.y);
        acc.z = fmaf(v, wv[j].z, acc.z); acc.w = fmaf(v, wv[j].w, acc.w);
      }
    }
    ((float4*)(red + s * 192))[q] = acc;
  }
  __syncthreads();
  if (t < 192) {
    float a = fb2[t];
#pragma unroll
    for (int s2 = 0; s2 < 8; ++s2) a += red[s2 * 192 + t];
    param[b * 192 + t] = a;
  }
}

// ---------------------------------------------------------------------------
// Render. LUT entry e[k] = {S_k*norm/64, p_k*norm}; eval = one b64 LDS gather
// + one FMA. LUT built with a per-wave prefix scan (width-64 shfl_up).
__global__ __launch_bounds__(256) void k_render(
    const float* __restrict__ x, const float* __restrict__ ws,
    float* __restrict__ out) {
  int b = blockIdx.y, t = threadIdx.x;
  int wave = t >> 6, lane = t & 63;
  const float* outs  = ws;
  const float* param = ws + 6144;
  __shared__ float2 tab[576];

  for (int cur = wave; cur < 9; cur += 4) {
    int oi = cur / 3, c = cur - oi * 3;
    const float* src = (oi == 0) ? param + b * 192 + c * 64
                                 : outs + ((oi - 1) * 8 + b) * 192 + c * 64;
    float p = src[lane];
    float v = p;  // inclusive scan
#pragma unroll
    for (int d = 1; d < 64; d <<= 1) {
      float n = __shfl_up(v, d, 64);
      if (lane >= d) v += n;
    }
    float total = __shfl(v, 63, 64);
    float norm = 64.f / (total + 1e-30f);
    float ex = v - p;  // exclusive prefix S_k
    tab[cur * 64 + lane] = make_float2(ex * 0.015625f * norm, p * norm);
  }
  __syncthreads();

  auto ev = [&](int cur, float v) -> float {
    int k = (int)(v * 64.f);
    k = k < 0 ? 0 : (k > 63 ? 63 : k);
    float2 e = tab[cur * 64 + k];
    float tt = v - (float)k * 0.015625f;
    return fmaf(tt, e.y, e.x);
  };
  auto ev4 = [&](int cur, float4 v) -> float4 {
    float4 r;
    r.x = ev(cur, v.x); r.y = ev(cur, v.y);
    r.z = ev(cur, v.z); r.w = ev(cur, v.w);
    return r;
  };

  int s4 = blockIdx.x * 256 + t;
  const float* xb = x + (size_t)b * PLANE;
  float4 vr = ((const float4*)(xb))[s4];
  float4 vg = ((const float4*)(xb + HWSZ))[s4];
  float4 vb = ((const float4*)(xb + 2 * HWSZ))[s4];

  float4 gr;
  gr.x = fmaf(0.299f, vr.x, fmaf(0.587f, vg.x, 0.114f * vb.x));
  gr.y = fmaf(0.299f, vr.y, fmaf(0.587f, vg.y, 0.114f * vb.y));
  gr.z = fmaf(0.299f, vr.z, fmaf(0.587f, vg.z, 0.114f * vb.z));
  gr.w = fmaf(0.299f, vr.w, fmaf(0.587f, vg.w, 0.114f * vb.w));

  float* o0 = out + (size_t)b * PLANE;
  float* o1 = out + OUTSTRIDE + (size_t)b * PLANE;
  float* o2 = out + 2 * OUTSTRIDE + (size_t)b * PLANE;

  ((float4*)(o0))[s4]            = ev4(0, vr);
  ((float4*)(o0 + HWSZ))[s4]     = ev4(1, vg);
  ((float4*)(o0 + 2 * HWSZ))[s4] = ev4(2, vb);
  ((float4*)(o1))[s4]            = ev4(3, gr);
  ((float4*)(o1 + HWSZ))[s4]     = ev4(4, gr);
  ((float4*)(o1 + 2 * HWSZ))[s4] = ev4(5, gr);
  ((float4*)(o2))[s4]            = ev4(6, gr);
  ((float4*)(o2 + HWSZ))[s4]     = ev4(7, gr);
  ((float4*)(o2 + 2 * HWSZ))[s4] = ev4(8, gr);
}

// ---------------------------------------------------------------------------
extern "C" void kernel_launch(void* const* d_in, const int* in_sizes, int n_in,
                              void* d_out, int out_size, void* d_ws, size_t ws_size,
                              hipStream_t stream) {
  const float* x   = (const float*)d_in[0];
  const float* f   = (const float*)d_in[1];
  const float* bf  = (const float*)d_in[2];
  const float* pw1 = (const float*)d_in[3];
  const float* pb1 = (const float*)d_in[4];
  const float* pw2 = (const float*)d_in[5];
  const float* pb2 = (const float*)d_in[6];
  const float* fw1 = (const float*)d_in[7];
  const float* fb1 = (const float*)d_in[8];
  const float* fw2 = (const float*)d_in[9];
  const float* fb2 = (const float*)d_in[10];
  float* out = (float*)d_out;
  float* ws  = (float*)d_ws;

  float* outs  = ws;         // [4,8,192] = 6144
  float* param = ws + 6144;  // [8,192]   = 1536

  k_proj<<<32, 384, 0, stream>>>(f, bf, pw1, pb1, pw2, pb2, outs);
  k_fcat<<<8, 384, 0, stream>>>(outs, fw1, fb1, fw2, fb2, param);
  dim3 grid(64, 8);
  k_render<<<grid, 256, 0, stream>>>(x, ws, out);
}